// Round 7
// baseline (277.522 us; speedup 1.0000x reference)
//
#include <hip/hip_runtime.h>
#include <math.h>

#define N_NODES   30000
#define N_EDGE    300000
#define N_EDGE_T  330000   // + self loops
#define HEADS     8
#define HIDDEN    64
#define IN_DIM    8
#define OUT_DIM   8
#define NEG_SLOPE 0.2f
#define MAX_STAGE 64       // edges staged in LDS per node (P[deg+1>64] ~ 0)

typedef float v2f __attribute__((ext_vector_type(2)));   // -> v_pk_fma_f32

// ---------------- CSR build ----------------

__global__ __launch_bounds__(256) void count_kernel(const int* __restrict__ ei,
                                                    int* __restrict__ count) {
    int e = blockIdx.x * 256 + threadIdx.x;
    if (e >= N_EDGE_T) return;
    int d = (e < N_EDGE) ? ei[N_EDGE + e] : (e - N_EDGE);
    atomicAdd(&count[d], 1);
}

// Single-block scan, 8 ints/thread via 2x int4: 4 rounds.
__global__ __launch_bounds__(1024) void scan_kernel(const int* __restrict__ count,
                                                    int* __restrict__ row_start,
                                                    int* __restrict__ cursor) {
    __shared__ int wsum[16];
    const int tid  = threadIdx.x;
    const int wave = tid >> 6;
    const int lane = tid & 63;
    const int4* c4 = (const int4*)count;
    const int N4 = N_NODES / 4;              // 7500 int4s exactly
    int run = 0;
    for (int r = 0; r < 4; ++r) {
        const int g  = r * 1024 + tid;
        const int i0 = 2 * g;
        const int i1 = 2 * g + 1;
        int4 v0 = make_int4(0,0,0,0), v1 = make_int4(0,0,0,0);
        if (i0 < N4) v0 = c4[i0];
        if (i1 < N4) v1 = c4[i1];
        int s = v0.x + v0.y + v0.z + v0.w + v1.x + v1.y + v1.z + v1.w;
        int sc = s;
        #pragma unroll
        for (int off = 1; off < 64; off <<= 1) {
            int t = __shfl_up(sc, off, 64);
            if (lane >= off) sc += t;
        }
        if (lane == 63) wsum[wave] = sc;
        __syncthreads();
        if (tid < 16) {
            int w = wsum[tid];
            #pragma unroll
            for (int off = 1; off < 16; off <<= 1) {
                int t = __shfl_up(w, off, 64);
                if (tid >= off) w += t;
            }
            wsum[tid] = w;
        }
        __syncthreads();
        const int woff = (wave > 0) ? wsum[wave - 1] : 0;
        int e0 = run + woff + (sc - s);
        int4 ex0, ex1;
        ex0.x = e0;           ex0.y = ex0.x + v0.x;
        ex0.z = ex0.y + v0.y; ex0.w = ex0.z + v0.z;
        int e4 = ex0.w + v0.w;
        ex1.x = e4;           ex1.y = ex1.x + v1.x;
        ex1.z = ex1.y + v1.y; ex1.w = ex1.z + v1.z;
        if (i0 < N4) { ((int4*)row_start)[i0] = ex0; ((int4*)cursor)[i0] = ex0; }
        if (i1 < N4) { ((int4*)row_start)[i1] = ex1; ((int4*)cursor)[i1] = ex1; }
        const int tot = wsum[15];
        __syncthreads();
        run += tot;
    }
    if (tid == 0) row_start[N_NODES] = run;
}

__global__ __launch_bounds__(256) void scatter_kernel(const int* __restrict__ ei,
                                                      int* __restrict__ cursor,
                                                      int* __restrict__ edge_src) {
    int e = blockIdx.x * 256 + threadIdx.x;
    if (e >= N_EDGE_T) return;
    int s, d;
    if (e < N_EDGE) { s = ei[e]; d = ei[N_EDGE + e]; }
    else            { s = d = e - N_EDGE; }
    int pos = atomicAdd(&cursor[d], 1);
    edge_src[pos] = s;
}

// ---------------- Layer 1 ----------------
// 256-thread block = 2 nodes (128 threads each = 2 waves). Per node:
// head = t128>>4, c4 = t128&15 -> 4 channels (2x v2f).
// Row's edge features staged into LDS at block start (one coalesced gather),
// hot loop reads broadcast ds_read_b128 -> no global latency in-loop.
// Unstabilized softmax (Glorot => logits O(1)); fold-reduce epilogue.

__device__ __forceinline__ void l1_batch(const float xf[4][IN_DIM],
                                         const v2f wl[IN_DIM][2],
                                         const v2f av0, const v2f av1,
                                         const v2f xr0, const v2f xr1,
                                         int nvalid,            // rowlen - base
                                         float& denom, v2f& acc0, v2f& acc1)
{
    v2f xl[4][2];
    #pragma unroll
    for (int e = 0; e < 4; ++e) { xl[e][0] = v2f{0.f, 0.f}; xl[e][1] = v2f{0.f, 0.f}; }
    #pragma unroll
    for (int k = 0; k < IN_DIM; ++k) {
        #pragma unroll
        for (int e = 0; e < 4; ++e) {
            v2f xs = {xf[e][k], xf[e][k]};
            xl[e][0] = __builtin_elementwise_fma(xs, wl[k][0], xl[e][0]);
            xl[e][1] = __builtin_elementwise_fma(xs, wl[k][1], xl[e][1]);
        }
    }
    float eh[4];
    #pragma unroll
    for (int e = 0; e < 4; ++e) {
        v2f v0 = xl[e][0] + xr0;
        v2f v1 = xl[e][1] + xr1;
        v2f t0 = __builtin_elementwise_max(v0, v0 * NEG_SLOPE);
        v2f t1 = __builtin_elementwise_max(v1, v1 * NEG_SLOPE);
        v2f s2 = __builtin_elementwise_fma(av1, t1, av0 * t0);
        eh[e] = s2.x + s2.y;
    }
    #pragma unroll
    for (int off = 1; off < 16; off <<= 1) {
        #pragma unroll
        for (int e = 0; e < 4; ++e) eh[e] += __shfl_xor(eh[e], off, 64);
    }
    float p[4];
    #pragma unroll
    for (int e = 0; e < 4; ++e) p[e] = (e < nvalid) ? __expf(eh[e]) : 0.f;
    denom += (p[0] + p[1]) + (p[2] + p[3]);
    #pragma unroll
    for (int e = 0; e < 4; ++e) {
        v2f ps = {p[e], p[e]};
        acc0 = __builtin_elementwise_fma(ps, xl[e][0], acc0);
        acc1 = __builtin_elementwise_fma(ps, xl[e][1], acc1);
    }
}

__global__ __launch_bounds__(256, 4) void layer1_kernel(
    const float* __restrict__ x,
    const float* __restrict__ W1l, const float* __restrict__ W1r,
    const float* __restrict__ a1,  const float* __restrict__ b1,
    const float* __restrict__ W2l, const float* __restrict__ W2r,
    const int* __restrict__ row_start, const int* __restrict__ edge_src,
    float* __restrict__ xl2, float* __restrict__ xr2)
{
    __shared__ float lds_x[2][MAX_STAGE][IN_DIM];   // 4 KB: staged edge features
    __shared__ float lds_red[2][HEADS][16];          // 1 KB: epilogue partials

    const int tid  = threadIdx.x;       // 0..255
    const int node = tid >> 7;          // 0..1
    const int t128 = tid & 127;
    const int head = t128 >> 4;         // 0..7
    const int c4   = t128 & 15;
    const int d    = blockIdx.x * 2 + node;
    const int colb = head * HIDDEN + c4 * 4;

    const int rs = row_start[d];
    const int re = row_start[d + 1];
    const int rowlen = re - rs;

    // ---- stage up to MAX_STAGE edges' features (coalesced, once per block) ----
    {
        const int slot = t128 >> 1, half = t128 & 1;
        int idx = rs + slot; if (idx > N_EDGE_T - 1) idx = N_EDGE_T - 1;  // clamp: real entry
        const int s = edge_src[idx];                                      // real node id
        const float4 v = *(const float4*)(x + s * IN_DIM + half * 4);
        *(float4*)&lds_x[node][slot][half * 4] = v;
    }

    // ---- prologue (overlaps staging latency) ----
    v2f wl[IN_DIM][2], av0, av1;
    #pragma unroll
    for (int k = 0; k < IN_DIM; ++k) {
        const float4 l4 = *(const float4*)&W1l[k * 512 + colb];
        wl[k][0] = v2f{l4.x, l4.y};
        wl[k][1] = v2f{l4.z, l4.w};
    }
    { const float4 a4 = *(const float4*)&a1[colb];
      av0 = v2f{a4.x, a4.y}; av1 = v2f{a4.z, a4.w}; }

    v2f xr0 = v2f{0.f, 0.f}, xr1 = v2f{0.f, 0.f};
    #pragma unroll
    for (int k = 0; k < IN_DIM; ++k) {
        const float xv = x[d * IN_DIM + k];
        const float4 r4 = *(const float4*)&W1r[k * 512 + colb];
        v2f xs = {xv, xv};
        xr0 = __builtin_elementwise_fma(xs, v2f{r4.x, r4.y}, xr0);
        xr1 = __builtin_elementwise_fma(xs, v2f{r4.z, r4.w}, xr1);
    }

    __syncthreads();   // staging complete

    float denom = 0.f;
    v2f acc0 = v2f{0.f, 0.f}, acc1 = v2f{0.f, 0.f};

    const int n_stage = rowlen < MAX_STAGE ? rowlen : MAX_STAGE;
    for (int base = 0; base < n_stage; base += 4) {
        float xf[4][IN_DIM];
        #pragma unroll
        for (int e = 0; e < 4; ++e) {
            int slot = base + e; if (slot > MAX_STAGE - 1) slot = MAX_STAGE - 1;
            const float4 u0 = *(const float4*)&lds_x[node][slot][0];
            const float4 u1 = *(const float4*)&lds_x[node][slot][4];
            xf[e][0] = u0.x; xf[e][1] = u0.y; xf[e][2] = u0.z; xf[e][3] = u0.w;
            xf[e][4] = u1.x; xf[e][5] = u1.y; xf[e][6] = u1.z; xf[e][7] = u1.w;
        }
        l1_batch(xf, wl, av0, av1, xr0, xr1, rowlen - base, denom, acc0, acc1);
    }
    // overflow path (rowlen > 64: astronomically rare, correctness only)
    for (int base = MAX_STAGE; base < rowlen; base += 4) {
        float xf[4][IN_DIM];
        #pragma unroll
        for (int e = 0; e < 4; ++e) {
            int idx = rs + base + e; if (idx > re - 1) idx = re - 1;
            const int s = edge_src[idx];
            const float4 u0 = *(const float4*)(x + s * IN_DIM);
            const float4 u1 = *(const float4*)(x + s * IN_DIM + 4);
            xf[e][0] = u0.x; xf[e][1] = u0.y; xf[e][2] = u0.z; xf[e][3] = u0.w;
            xf[e][4] = u1.x; xf[e][5] = u1.y; xf[e][6] = u1.z; xf[e][7] = u1.w;
        }
        l1_batch(xf, wl, av0, av1, xr0, xr1, rowlen - base, denom, acc0, acc1);
    }

    const float inv = 1.f / denom;
    const float4 b4 = *(const float4*)&b1[colb];
    float hv[4];
    hv[0] = fmaxf(acc0.x * inv + b4.x, 0.f);
    hv[1] = fmaxf(acc0.y * inv + b4.y, 0.f);
    hv[2] = fmaxf(acc1.x * inv + b4.z, 0.f);
    hv[3] = fmaxf(acc1.y * inv + b4.w, 0.f);

    // ---- epilogue: w[0..8) = partial xl2[j], w[8..16) = partial xr2[j] ----
    float w[16];
    #pragma unroll
    for (int j = 0; j < 16; ++j) w[j] = 0.f;
    #pragma unroll
    for (int i = 0; i < 4; ++i) {
        const float4 l0 = *(const float4*)&W2l[(colb + i) * OUT_DIM];
        const float4 l1 = *(const float4*)&W2l[(colb + i) * OUT_DIM + 4];
        const float4 r0 = *(const float4*)&W2r[(colb + i) * OUT_DIM];
        const float4 r1 = *(const float4*)&W2r[(colb + i) * OUT_DIM + 4];
        w[0]  = fmaf(hv[i], l0.x, w[0]);  w[1]  = fmaf(hv[i], l0.y, w[1]);
        w[2]  = fmaf(hv[i], l0.z, w[2]);  w[3]  = fmaf(hv[i], l0.w, w[3]);
        w[4]  = fmaf(hv[i], l1.x, w[4]);  w[5]  = fmaf(hv[i], l1.y, w[5]);
        w[6]  = fmaf(hv[i], l1.z, w[6]);  w[7]  = fmaf(hv[i], l1.w, w[7]);
        w[8]  = fmaf(hv[i], r0.x, w[8]);  w[9]  = fmaf(hv[i], r0.y, w[9]);
        w[10] = fmaf(hv[i], r0.z, w[10]); w[11] = fmaf(hv[i], r0.w, w[11]);
        w[12] = fmaf(hv[i], r1.x, w[12]); w[13] = fmaf(hv[i], r1.y, w[13]);
        w[14] = fmaf(hv[i], r1.z, w[14]); w[15] = fmaf(hv[i], r1.w, w[15]);
    }
    // fold-reduce: 16 values x 16 lanes -> lane c4 owns output o=c4 (15 shuffles)
    {   // r = 8
        const bool up = (c4 & 8) != 0;
        #pragma unroll
        for (int i = 0; i < 8; ++i) {
            float send = up ? w[i] : w[i + 8];
            float recv = __shfl_xor(send, 8, 64);
            w[i] = (up ? w[i + 8] : w[i]) + recv;
        }
    }
    {   // r = 4
        const bool up = (c4 & 4) != 0;
        #pragma unroll
        for (int i = 0; i < 4; ++i) {
            float send = up ? w[i] : w[i + 4];
            float recv = __shfl_xor(send, 4, 64);
            w[i] = (up ? w[i + 4] : w[i]) + recv;
        }
    }
    {   // r = 2
        const bool up = (c4 & 2) != 0;
        #pragma unroll
        for (int i = 0; i < 2; ++i) {
            float send = up ? w[i] : w[i + 2];
            float recv = __shfl_xor(send, 2, 64);
            w[i] = (up ? w[i + 2] : w[i]) + recv;
        }
    }
    {   // r = 1
        const bool up = (c4 & 1) != 0;
        float send = up ? w[0] : w[1];
        float recv = __shfl_xor(send, 1, 64);
        w[0] = (up ? w[1] : w[0]) + recv;
    }
    lds_red[node][head][c4] = w[0];
    __syncthreads();
    if (t128 < 16) {
        float s = 0.f;
        #pragma unroll
        for (int h = 0; h < HEADS; ++h) s += lds_red[node][h][t128];
        const int side = t128 >> 3, j = t128 & 7;
        if (side == 0) xl2[d * OUT_DIM + j] = s;
        else           xr2[d * OUT_DIM + j] = s;
    }
}

// ---------------- Layer 2 (1 head, dim 8) ----------------

__global__ __launch_bounds__(256) void layer2_kernel(
    const float* __restrict__ xl2, const float* __restrict__ xr2,
    const float* __restrict__ a2,  const float* __restrict__ b2,
    const int* __restrict__ row_start, const int* __restrict__ edge_src,
    float* __restrict__ out)
{
    const int wave = threadIdx.x >> 6;
    const int lane = threadIdx.x & 63;
    const int d = blockIdx.x * 4 + wave;
    if (d >= N_NODES) return;
    const int sub = lane >> 3;   // edge slot 0..7
    const int c   = lane & 7;    // channel

    const float a_c  = a2[c];
    const float xr_d = xr2[d * OUT_DIM + c];

    const int rs = row_start[d];
    const int re = row_start[d + 1];

    float denom = 0.f, acc = 0.f;

    for (int base = rs; base < re; base += 8) {
        int e = base + sub;
        bool valid = (e < re);
        int s = valid ? edge_src[e] : 0;
        float xls = xl2[s * OUT_DIM + c];
        float v = xls + xr_d;
        float t = fmaxf(v, NEG_SLOPE * v);
        float eh = a_c * t;
        eh += __shfl_xor(eh, 1, 64);
        eh += __shfl_xor(eh, 2, 64);
        eh += __shfl_xor(eh, 4, 64);
        float p = valid ? __expf(eh) : 0.f;
        denom += p;
        acc = fmaf(p, xls, acc);
    }

    denom += __shfl_xor(denom, 8,  64);  acc += __shfl_xor(acc, 8,  64);
    denom += __shfl_xor(denom, 16, 64);  acc += __shfl_xor(acc, 16, 64);
    denom += __shfl_xor(denom, 32, 64);  acc += __shfl_xor(acc, 32, 64);

    if (sub == 0) out[d * OUT_DIM + c] = acc / denom + b2[c];
}

// ---------------- launch ----------------

extern "C" void kernel_launch(void* const* d_in, const int* in_sizes, int n_in,
                              void* d_out, int out_size, void* d_ws, size_t ws_size,
                              hipStream_t stream) {
    const float* x   = (const float*)d_in[0];
    const int*   ei  = (const int*)  d_in[1];
    const float* W1l = (const float*)d_in[2];
    const float* W1r = (const float*)d_in[3];
    const float* a1  = (const float*)d_in[4];
    const float* b1  = (const float*)d_in[5];
    const float* W2l = (const float*)d_in[6];
    const float* W2r = (const float*)d_in[7];
    const float* a2  = (const float*)d_in[8];
    const float* b2  = (const float*)d_in[9];
    float* out = (float*)d_out;

    char* ws = (char*)d_ws;
    size_t off = 0;
    auto carve = [&](size_t bytes) { char* p = ws + off; off += (bytes + 255) & ~size_t(255); return p; };
    int*   count     = (int*)  carve(N_NODES * sizeof(int));
    int*   row_start = (int*)  carve((N_NODES + 1) * sizeof(int));
    int*   cursor    = (int*)  carve(N_NODES * sizeof(int));
    int*   edge_src  = (int*)  carve((N_EDGE_T + 8) * sizeof(int));
    float* xl2       = (float*)carve(N_NODES * OUT_DIM * sizeof(float));
    float* xr2       = (float*)carve(N_NODES * OUT_DIM * sizeof(float));

    hipMemsetAsync(count, 0, N_NODES * sizeof(int), stream);
    count_kernel  <<<(N_EDGE_T + 255) / 256, 256, 0, stream>>>(ei, count);
    scan_kernel   <<<1, 1024, 0, stream>>>(count, row_start, cursor);
    scatter_kernel<<<(N_EDGE_T + 255) / 256, 256, 0, stream>>>(ei, cursor, edge_src);
    layer1_kernel <<<N_NODES / 2, 256, 0, stream>>>(x, W1l, W1r, a1, b1, W2l, W2r,
                                                    row_start, edge_src, xl2, xr2);
    layer2_kernel <<<(N_NODES + 3) / 4, 256, 0, stream>>>(xl2, xr2, a2, b2,
                                                          row_start, edge_src, out);
}